// Round 6
// baseline (148.341 us; speedup 1.0000x reference)
//
#include <hip/hip_runtime.h>
#include <math.h>

constexpr int N = 2048;   // batch
constexpr int P = 1024;   // p
constexpr int D = 256;    // d
constexpr float TAU = 18.0f;

constexpr size_t OFF_XHAT  = 0;
constexpr size_t OFF_YHAT  = (size_t)N * D;
constexpr size_t OFF_XBOX  = 2 * (size_t)N * D;
constexpr size_t OFF_YBOX  = 3 * (size_t)N * D;
constexpr size_t OFF_YPRED = 4 * (size_t)N * D;
constexpr size_t OFF_SREC  = 5 * (size_t)N * D;

// workspace byte offsets
constexpr size_t WS_ATH = 0;          // At hi  [256][1024] bf16
constexpr size_t WS_ATL = 524288;     // At lo
constexpr size_t WS_BTH = 1048576;    // Bt hi  [1024][256] bf16
constexpr size_t WS_BTL = 1572864;    // Bt lo
constexpr size_t WS_V   = 2097152;    // V [256][256] f32
constexpr size_t WS_U   = 2359296;    // U [2048][256] f32
constexpr size_t WS_LHH = 4456448;    // LHS hi [6144][256] bf16 (Xh,Yh,Ypred)
constexpr size_t WS_LHL = 7602176;    // LHS lo

typedef short bhalf8 __attribute__((ext_vector_type(8)));
typedef float f32x4  __attribute__((ext_vector_type(4)));

__device__ inline short f2bf(float f) {
  union { float f; unsigned u; } x; x.f = f;
  unsigned r = (x.u + 0x7FFFu + ((x.u >> 16) & 1u)) >> 16;
  return (short)r;
}
__device__ inline float bf2f(short h) {
  union { unsigned u; float f; } x; x.u = ((unsigned)(unsigned short)h) << 16;
  return x.f;
}

// ---------------------------------------------------------------------------
// merged prep: [0,64) V=exp(-tau*sigmoid(rawM)); [64,320) transpose+split A;
// [320,576) transpose+split B.  One launch instead of three.
// ---------------------------------------------------------------------------
__device__ inline void transpose_hilo_body(
    const float* __restrict__ src, short* __restrict__ dh,
    short* __restrict__ dl, int R, int C, int bx, int by, int t) {
  __shared__ __align__(16) float tile[32][36];
  const int r0 = bx * 32, c0 = by * 32;
  {
    const int tr = t >> 3, tc4 = (t & 7) * 4;
    float4 x = *(const float4*)(src + (size_t)(r0 + tr) * C + c0 + tc4);
    *(float4*)&tile[tr][tc4] = x;
  }
  __syncthreads();
  {
    const int tc = t >> 3, tr4 = (t & 7) * 4;
    short4 h, l;
    float f0 = tile[tr4 + 0][tc];
    float f1 = tile[tr4 + 1][tc];
    float f2 = tile[tr4 + 2][tc];
    float f3 = tile[tr4 + 3][tc];
    h.x = f2bf(f0); l.x = f2bf(f0 - bf2f(h.x));
    h.y = f2bf(f1); l.y = f2bf(f1 - bf2f(h.y));
    h.z = f2bf(f2); l.z = f2bf(f2 - bf2f(h.z));
    h.w = f2bf(f3); l.w = f2bf(f3 - bf2f(h.w));
    *(short4*)(dh + (size_t)(c0 + tc) * R + r0 + tr4) = h;
    *(short4*)(dl + (size_t)(c0 + tc) * R + r0 + tr4) = l;
  }
}

__global__ __launch_bounds__(256) void prep_all_kernel(
    const float* __restrict__ A, const float* __restrict__ rawM,
    const float* __restrict__ B, short* __restrict__ Ath,
    short* __restrict__ Atl, short* __restrict__ Bth,
    short* __restrict__ Btl, float* __restrict__ V) {
  const int bid = blockIdx.x;
  const int t = threadIdx.x;
  if (bid < 64) {
    const int idx = (bid * 256 + t) * 4;
    float4 x = *(const float4*)(rawM + idx);
    float4 o;
    o.x = expf(-TAU / (1.0f + expf(-x.x)));
    o.y = expf(-TAU / (1.0f + expf(-x.y)));
    o.z = expf(-TAU / (1.0f + expf(-x.z)));
    o.w = expf(-TAU / (1.0f + expf(-x.w)));
    *(float4*)(V + idx) = o;
  } else if (bid < 320) {
    const int idx = bid - 64;           // A: R=1024, C=256, grid 32x8
    transpose_hilo_body(A, Ath, Atl, P, D, idx & 31, idx >> 5, t);
  } else {
    const int idx = bid - 320;          // B: R=256, C=1024, grid 8x32
    transpose_hilo_body(B, Bth, Btl, D, P, idx & 7, idx >> 3, t);
  }
}

// ---------------------------------------------------------------------------
// GEMM1 (MFMA): C[4096][256] = [S;T] @ A, 3-term split (hh+hl+lh).
// BM=32 BN=64 BK=32, 256 thr = 4 waves (2x2 of 16x32 tiles), dbuf LDS,
// 1 barrier/k-step. 30KB LDS -> ~2 blocks resident/CU. grid (128, 4).
// Epilogue: hats, boxes, U, bf16 hi/lo LHS rows for gemm2.
// ---------------------------------------------------------------------------
__global__ __launch_bounds__(256) void gemm1_mfma(
    const float* __restrict__ S, const float* __restrict__ Tm,
    const short* __restrict__ Ath, const short* __restrict__ Atl,
    float* __restrict__ out, float* __restrict__ U,
    short* __restrict__ LHh, short* __restrict__ LHl) {
  __shared__ __align__(16) short As_h[2][32][40];
  __shared__ __align__(16) short As_l[2][32][40];
  __shared__ __align__(16) short Bs_h[2][64][40];
  __shared__ __align__(16) short Bs_l[2][64][40];

  const int t  = threadIdx.x;
  const int m0 = blockIdx.x * 32, n0 = blockIdx.y * 64;

  // A staging: 8 lanes/row, 4 k each (32 rows x 32 k fp32)
  const int arow = t >> 3;
  const int ak   = (t & 7) * 4;
  const int grow = m0 + arow;
  const float* Lrow = (grow < N) ? (S + (size_t)grow * P)
                                 : (Tm + (size_t)(grow - N) * P);
  // B staging: 4 lanes/row, 8 k each (64 rows x 32 k bf16 h/l)
  const int brow = t >> 2;
  const int bk   = (t & 3) * 8;
  const short* BhR = Ath + (size_t)(n0 + brow) * P;
  const short* BlR = Atl + (size_t)(n0 + brow) * P;

  // compute ids: 4 waves, 2(m) x 2(n), wave tile 16x32
  const int l = t & 63, w = t >> 6;
  const int wr = (w & 1) * 16, wc = (w >> 1) * 32;
  const int fr = l & 15, ko8 = (l >> 4) * 8, rq = (l >> 4) * 4;

  f32x4 acc[2];
  acc[0] = (f32x4){0.f, 0.f, 0.f, 0.f};
  acc[1] = (f32x4){0.f, 0.f, 0.f, 0.f};

  float4 pa  = *(const float4*)(Lrow + ak);
  bhalf8 pbh = *(const bhalf8*)(BhR + bk);
  bhalf8 pbl = *(const bhalf8*)(BlR + bk);

#define STAGE1(buf)                                        \
  do {                                                     \
    short4 ah4, al4;                                       \
    ah4.x = f2bf(pa.x); al4.x = f2bf(pa.x - bf2f(ah4.x));  \
    ah4.y = f2bf(pa.y); al4.y = f2bf(pa.y - bf2f(ah4.y));  \
    ah4.z = f2bf(pa.z); al4.z = f2bf(pa.z - bf2f(ah4.z));  \
    ah4.w = f2bf(pa.w); al4.w = f2bf(pa.w - bf2f(ah4.w));  \
    *(short4*)&As_h[buf][arow][ak] = ah4;                  \
    *(short4*)&As_l[buf][arow][ak] = al4;                  \
    *(bhalf8*)&Bs_h[buf][brow][bk] = pbh;                  \
    *(bhalf8*)&Bs_l[buf][brow][bk] = pbl;                  \
  } while (0)

  STAGE1(0);

  for (int ks = 0; ks < 32; ++ks) {
    const int b = ks & 1;
    if (ks < 31) {
      const int kn = (ks + 1) * 32;
      pa  = *(const float4*)(Lrow + kn + ak);
      pbh = *(const bhalf8*)(BhR + kn + bk);
      pbl = *(const bhalf8*)(BlR + kn + bk);
    }
    __syncthreads();
    bhalf8 ahv = *(const bhalf8*)&As_h[b][wr + fr][ko8];
    bhalf8 alv = *(const bhalf8*)&As_l[b][wr + fr][ko8];
#pragma unroll
    for (int ni = 0; ni < 2; ++ni) {
      bhalf8 bhv = *(const bhalf8*)&Bs_h[b][wc + ni * 16 + fr][ko8];
      bhalf8 blv = *(const bhalf8*)&Bs_l[b][wc + ni * 16 + fr][ko8];
      acc[ni] = __builtin_amdgcn_mfma_f32_16x16x32_bf16(ahv, bhv, acc[ni], 0, 0, 0);
      acc[ni] = __builtin_amdgcn_mfma_f32_16x16x32_bf16(ahv, blv, acc[ni], 0, 0, 0);
      acc[ni] = __builtin_amdgcn_mfma_f32_16x16x32_bf16(alv, bhv, acc[ni], 0, 0, 0);
    }
    if (ks < 31) STAGE1((ks + 1) & 1);
  }
#undef STAGE1

#pragma unroll
  for (int ni = 0; ni < 2; ++ni) {
    const int col = n0 + wc + ni * 16 + fr;
#pragma unroll
    for (int r = 0; r < 4; ++r) {
      const int row = m0 + wr + rq + r;
      const float v = acc[ni][r];
      const float c = fminf(fmaxf(v, 0.0f), 1.0f);
      const short h  = f2bf(v);
      const short lo = f2bf(v - bf2f(h));
      LHh[(size_t)row * D + col] = h;
      LHl[(size_t)row * D + col] = lo;
      if (row < N) {
        out[OFF_XHAT + (size_t)row * D + col] = v;
        out[OFF_XBOX + (size_t)row * D + col] = c;
        U[(size_t)row * D + col] = expf(-TAU * c);
      } else {
        const size_t ry = (size_t)(row - N);
        out[OFF_YHAT + ry * D + col] = v;
        out[OFF_YBOX + ry * D + col] = c;
      }
    }
  }
}

// ---------------------------------------------------------------------------
// smooth: Y_pred[n][j] = (1/tau) * log( sum_i rcp(U[n][i] + V[i][j]) )
// tile 16n x 32j, micro 1n x 2j; grid (128, 8) = 1024 blocks, 256 threads.
// Epilogue also writes bf16 hi/lo of Y_pred into LHS rows 4096+.
// ---------------------------------------------------------------------------
__global__ __launch_bounds__(256) void smooth_kernel(
    const float* __restrict__ U, const float* __restrict__ V,
    float* __restrict__ ypred, short* __restrict__ LHh,
    short* __restrict__ LHl) {
  __shared__ float us[256][17];   // us[i][n]
  const int t = threadIdx.x;
  const int n0 = blockIdx.x * 16, j0 = blockIdx.y * 32;

  {
    const int sr = t & 15;            // n within tile
    const int si = (t >> 4) * 16;     // i-chunk
    const float* up = U + (size_t)(n0 + sr) * D + si;
#pragma unroll
    for (int q = 0; q < 16; q += 4) {
      float4 x = *(const float4*)(up + q);
      us[si + q + 0][sr] = x.x;
      us[si + q + 1][sr] = x.y;
      us[si + q + 2][sr] = x.z;
      us[si + q + 3][sr] = x.w;
    }
  }
  __syncthreads();

  const int jg = (t & 15) * 2;
  const int nn = t >> 4;              // 0..15
  const float* vp = V + j0 + jg;

  float acc0 = 0.f, acc1 = 0.f;
#pragma unroll 8
  for (int i = 0; i < D; ++i) {
    const float u = us[i][nn];
    float2 v2 = *(const float2*)(vp + (size_t)i * D);
    acc0 += __builtin_amdgcn_rcpf(u + v2.x);
    acc1 += __builtin_amdgcn_rcpf(u + v2.y);
  }

  const int row = n0 + nn;
  float2 o;
  o.x = (1.0f / TAU) * logf(acc0);
  o.y = (1.0f / TAU) * logf(acc1);
  *(float2*)(ypred + (size_t)row * D + j0 + jg) = o;
  short2 h2, l2;
  h2.x = f2bf(o.x); l2.x = f2bf(o.x - bf2f(h2.x));
  h2.y = f2bf(o.y); l2.y = f2bf(o.y - bf2f(h2.y));
  const size_t lrow = (size_t)(2 * N + row) * D + j0 + jg;
  *(short2*)(LHh + lrow) = h2;
  *(short2*)(LHl + lrow) = l2;
}

// ---------------------------------------------------------------------------
// GEMM2 (MFMA): C[6144][1024] = [X_hat;Y_hat;Y_pred] @ B, 3-term split.
// BM=64 BN=64 BK=32, 256 thr = 4 waves, wave tile 32x32 (2x2 frags):
// 12 MFMA per 8 LDS reads. dbuf, K=256 -> 8 steps. grid (96, 16).
// 40KB LDS -> 4 blocks/CU = 16 waves/CU.
// ---------------------------------------------------------------------------
__global__ __launch_bounds__(256) void gemm2_mfma(
    const short* __restrict__ LHh, const short* __restrict__ LHl,
    const short* __restrict__ Bth, const short* __restrict__ Btl,
    float* __restrict__ rec) {
  __shared__ __align__(16) short As_h[2][64][40];
  __shared__ __align__(16) short As_l[2][64][40];
  __shared__ __align__(16) short Bs_h[2][64][40];
  __shared__ __align__(16) short Bs_l[2][64][40];

  const int t  = threadIdx.x;
  const int m0 = blockIdx.x * 64, n0 = blockIdx.y * 64;

  // staging: 4 lanes/row, 8 k each (64 rows x 32 k, all bf16)
  const int srow = t >> 2;
  const int sk   = (t & 3) * 8;
  const short* AhR = LHh + (size_t)(m0 + srow) * D;
  const short* AlR = LHl + (size_t)(m0 + srow) * D;
  const short* BhR = Bth + (size_t)(n0 + srow) * D;
  const short* BlR = Btl + (size_t)(n0 + srow) * D;

  // compute ids: 4 waves 2x2, wave tile 32x32 (2x2 frags)
  const int l = t & 63, w = t >> 6;
  const int wr = (w & 1) * 32, wc = (w >> 1) * 32;
  const int fr = l & 15, ko8 = (l >> 4) * 8, rq = (l >> 4) * 4;

  f32x4 acc[2][2];
#pragma unroll
  for (int i = 0; i < 2; ++i)
#pragma unroll
    for (int j = 0; j < 2; ++j) acc[i][j] = (f32x4){0.f, 0.f, 0.f, 0.f};

  bhalf8 pah = *(const bhalf8*)(AhR + sk);
  bhalf8 pal = *(const bhalf8*)(AlR + sk);
  bhalf8 pbh = *(const bhalf8*)(BhR + sk);
  bhalf8 pbl = *(const bhalf8*)(BlR + sk);

#define STAGE2(buf)                            \
  do {                                         \
    *(bhalf8*)&As_h[buf][srow][sk] = pah;      \
    *(bhalf8*)&As_l[buf][srow][sk] = pal;      \
    *(bhalf8*)&Bs_h[buf][srow][sk] = pbh;      \
    *(bhalf8*)&Bs_l[buf][srow][sk] = pbl;      \
  } while (0)

  STAGE2(0);

  for (int ks = 0; ks < 8; ++ks) {
    const int b = ks & 1;
    if (ks < 7) {
      const int kn = (ks + 1) * 32;
      pah = *(const bhalf8*)(AhR + kn + sk);
      pal = *(const bhalf8*)(AlR + kn + sk);
      pbh = *(const bhalf8*)(BhR + kn + sk);
      pbl = *(const bhalf8*)(BlR + kn + sk);
    }
    __syncthreads();
    bhalf8 ahv[2], alv[2], bhv[2], blv[2];
#pragma unroll
    for (int mi = 0; mi < 2; ++mi) {
      ahv[mi] = *(const bhalf8*)&As_h[b][wr + mi * 16 + fr][ko8];
      alv[mi] = *(const bhalf8*)&As_l[b][wr + mi * 16 + fr][ko8];
      bhv[mi] = *(const bhalf8*)&Bs_h[b][wc + mi * 16 + fr][ko8];
      blv[mi] = *(const bhalf8*)&Bs_l[b][wc + mi * 16 + fr][ko8];
    }
#pragma unroll
    for (int mi = 0; mi < 2; ++mi)
#pragma unroll
      for (int ni = 0; ni < 2; ++ni) {
        acc[mi][ni] = __builtin_amdgcn_mfma_f32_16x16x32_bf16(ahv[mi], bhv[ni], acc[mi][ni], 0, 0, 0);
        acc[mi][ni] = __builtin_amdgcn_mfma_f32_16x16x32_bf16(ahv[mi], blv[ni], acc[mi][ni], 0, 0, 0);
        acc[mi][ni] = __builtin_amdgcn_mfma_f32_16x16x32_bf16(alv[mi], bhv[ni], acc[mi][ni], 0, 0, 0);
      }
    if (ks < 7) STAGE2((ks + 1) & 1);
  }
#undef STAGE2

#pragma unroll
  for (int mi = 0; mi < 2; ++mi)
#pragma unroll
    for (int ni = 0; ni < 2; ++ni) {
      const int col = n0 + wc + ni * 16 + fr;
#pragma unroll
      for (int r = 0; r < 4; ++r) {
        const int row = m0 + wr + mi * 16 + rq + r;
        rec[(size_t)row * P + col] = acc[mi][ni][r];
      }
    }
}

// ---------------------------------------------------------------------------
extern "C" void kernel_launch(void* const* d_in, const int* in_sizes, int n_in,
                              void* d_out, int out_size, void* d_ws,
                              size_t ws_size, hipStream_t stream) {
  const float* S    = (const float*)d_in[0];
  const float* T    = (const float*)d_in[1];
  const float* A    = (const float*)d_in[2];
  const float* rawM = (const float*)d_in[3];
  const float* B    = (const float*)d_in[4];
  float* out = (float*)d_out;
  char* ws = (char*)d_ws;

  short* Ath = (short*)(ws + WS_ATH);
  short* Atl = (short*)(ws + WS_ATL);
  short* Bth = (short*)(ws + WS_BTH);
  short* Btl = (short*)(ws + WS_BTL);
  float* V   = (float*)(ws + WS_V);
  float* U   = (float*)(ws + WS_U);
  short* LHh = (short*)(ws + WS_LHH);
  short* LHl = (short*)(ws + WS_LHL);

  prep_all_kernel<<<576, 256, 0, stream>>>(A, rawM, B, Ath, Atl, Bth, Btl, V);
  gemm1_mfma<<<dim3(128, 4), 256, 0, stream>>>(S, T, Ath, Atl, out, U, LHh, LHl);
  smooth_kernel<<<dim3(128, 8), 256, 0, stream>>>(U, V, out + OFF_YPRED, LHh, LHl);
  gemm2_mfma<<<dim3(96, 16), 256, 0, stream>>>(LHh, LHl, Bth, Btl, out + OFF_SREC);
}

// Round 8
// 133.658 us; speedup vs baseline: 1.1098x; 1.1098x over previous
//
#include <hip/hip_runtime.h>
#include <math.h>

constexpr int N = 2048;   // batch
constexpr int P = 1024;   // p
constexpr int D = 256;    // d
constexpr float TAU = 18.0f;

constexpr size_t OFF_XHAT  = 0;
constexpr size_t OFF_YHAT  = (size_t)N * D;
constexpr size_t OFF_XBOX  = 2 * (size_t)N * D;
constexpr size_t OFF_YBOX  = 3 * (size_t)N * D;
constexpr size_t OFF_YPRED = 4 * (size_t)N * D;
constexpr size_t OFF_SREC  = 5 * (size_t)N * D;

// workspace byte offsets
constexpr size_t WS_ATH = 0;          // At hi  [256][1024] bf16
constexpr size_t WS_ATL = 524288;     // At lo
constexpr size_t WS_BTH = 1048576;    // Bt hi  [1024][256] bf16
constexpr size_t WS_BTL = 1572864;    // Bt lo
constexpr size_t WS_V   = 2097152;    // V [256][256] f32
constexpr size_t WS_U   = 2359296;    // U [2048][256] f32
constexpr size_t WS_LHH = 4456448;    // LHS hi [6144][256] bf16 (Xh,Yh,Ypred)
constexpr size_t WS_LHL = 7602176;    // LHS lo
constexpr size_t WS_STH = 10747904;   // [S;T] hi [4096][1024] bf16
constexpr size_t WS_STL = 19136512;   // [S;T] lo

typedef short bhalf8 __attribute__((ext_vector_type(8)));
typedef float f32x4  __attribute__((ext_vector_type(4)));

__device__ inline short f2bf(float f) {
  union { float f; unsigned u; } x; x.f = f;
  unsigned r = (x.u + 0x7FFFu + ((x.u >> 16) & 1u)) >> 16;
  return (short)r;
}
__device__ inline float bf2f(short h) {
  union { unsigned u; float f; } x; x.u = ((unsigned)(unsigned short)h) << 16;
  return x.f;
}
// bijective XCD swizzle (requires nwg % 8 == 0)
__device__ inline int xcd_swz(int bid, int nwg) {
  const int cpx = nwg >> 3;
  return (bid & 7) * cpx + (bid >> 3);
}

// ---------------------------------------------------------------------------
// merged prep:
//   [0,64)      V = exp(-tau*sigmoid(rawM))
//   [64,320)    A  -> Ath/Atl   (transpose + hi/lo split)
//   [320,576)   B  -> Bth/Btl   (transpose + hi/lo split)
//   [576,1600)  S,T -> STh/STl  (hi/lo split, no transpose)
// ---------------------------------------------------------------------------
__device__ inline void transpose_hilo_body(
    const float* __restrict__ src, short* __restrict__ dh,
    short* __restrict__ dl, int R, int C, int bx, int by, int t) {
  __shared__ __align__(16) float tile[32][36];
  const int r0 = bx * 32, c0 = by * 32;
  {
    const int tr = t >> 3, tc4 = (t & 7) * 4;
    float4 x = *(const float4*)(src + (size_t)(r0 + tr) * C + c0 + tc4);
    *(float4*)&tile[tr][tc4] = x;
  }
  __syncthreads();
  {
    const int tc = t >> 3, tr4 = (t & 7) * 4;
    short4 h, l;
    float f0 = tile[tr4 + 0][tc];
    float f1 = tile[tr4 + 1][tc];
    float f2 = tile[tr4 + 2][tc];
    float f3 = tile[tr4 + 3][tc];
    h.x = f2bf(f0); l.x = f2bf(f0 - bf2f(h.x));
    h.y = f2bf(f1); l.y = f2bf(f1 - bf2f(h.y));
    h.z = f2bf(f2); l.z = f2bf(f2 - bf2f(h.z));
    h.w = f2bf(f3); l.w = f2bf(f3 - bf2f(h.w));
    *(short4*)(dh + (size_t)(c0 + tc) * R + r0 + tr4) = h;
    *(short4*)(dl + (size_t)(c0 + tc) * R + r0 + tr4) = l;
  }
}

__global__ __launch_bounds__(256) void prep_all_kernel(
    const float* __restrict__ S, const float* __restrict__ Tm,
    const float* __restrict__ A, const float* __restrict__ rawM,
    const float* __restrict__ B, short* __restrict__ Ath,
    short* __restrict__ Atl, short* __restrict__ Bth,
    short* __restrict__ Btl, float* __restrict__ V,
    short* __restrict__ STh, short* __restrict__ STl) {
  const int bid = blockIdx.x;
  const int t = threadIdx.x;
  if (bid < 64) {
    const int idx = (bid * 256 + t) * 4;
    float4 x = *(const float4*)(rawM + idx);
    float4 o;
    o.x = expf(-TAU / (1.0f + expf(-x.x)));
    o.y = expf(-TAU / (1.0f + expf(-x.y)));
    o.z = expf(-TAU / (1.0f + expf(-x.z)));
    o.w = expf(-TAU / (1.0f + expf(-x.w)));
    *(float4*)(V + idx) = o;
  } else if (bid < 320) {
    const int idx = bid - 64;           // A: R=1024, C=256
    transpose_hilo_body(A, Ath, Atl, P, D, idx & 31, idx >> 5, t);
  } else if (bid < 576) {
    const int idx = bid - 320;          // B: R=256, C=1024
    transpose_hilo_body(B, Bth, Btl, D, P, idx & 7, idx >> 3, t);
  } else {
    const int idx = bid - 576;          // 0..1023, 4 rows each
#pragma unroll
    for (int q = 0; q < 4; ++q) {
      const int row = idx * 4 + q;      // 0..4095
      const float* src = (row < N) ? (S + (size_t)row * P)
                                   : (Tm + (size_t)(row - N) * P);
      float4 x = *(const float4*)(src + t * 4);
      short4 h, l;
      h.x = f2bf(x.x); l.x = f2bf(x.x - bf2f(h.x));
      h.y = f2bf(x.y); l.y = f2bf(x.y - bf2f(h.y));
      h.z = f2bf(x.z); l.z = f2bf(x.z - bf2f(h.z));
      h.w = f2bf(x.w); l.w = f2bf(x.w - bf2f(h.w));
      *(short4*)(STh + (size_t)row * P + t * 4) = h;
      *(short4*)(STl + (size_t)row * P + t * 4) = l;
    }
  }
}

// ---------------------------------------------------------------------------
// GEMM1 (MFMA): C[4096][256] = [S;T] @ A, 3-term split (hh+hl+lh).
// BM=32 BN=64 BK=64, 256 thr = 4 waves (2x2 of 16x32 tiles), dbuf LDS,
// 16 k-steps (16 barriers). All operands pre-split bf16 -> pure-copy staging.
// 54KB LDS -> 2 blocks/CU. grid 512 flat, XCD-swizzled.
// Epilogue: hats, boxes, U, bf16 hi/lo LHS rows for gemm2.
// ---------------------------------------------------------------------------
__global__ __launch_bounds__(256) void gemm1_mfma(
    const short* __restrict__ STh, const short* __restrict__ STl,
    const short* __restrict__ Ath, const short* __restrict__ Atl,
    float* __restrict__ out, float* __restrict__ U,
    short* __restrict__ LHh, short* __restrict__ LHl) {
  __shared__ __align__(16) short As_h[2][32][72];
  __shared__ __align__(16) short As_l[2][32][72];
  __shared__ __align__(16) short Bs_h[2][64][72];
  __shared__ __align__(16) short Bs_l[2][64][72];

  const int t  = threadIdx.x;
  const int wg = xcd_swz(blockIdx.x, 512);
  const int m0 = (wg >> 2) * 32, n0 = (wg & 3) * 64;

  // A staging: 32 rows x 64 k, 8 lanes/row (bhalf8)
  const int arow = t >> 3;
  const int ak   = (t & 7) * 8;
  const short* AhR = STh + (size_t)(m0 + arow) * P;
  const short* AlR = STl + (size_t)(m0 + arow) * P;
  // B staging: 64 rows x 64 k, 4 lanes/row (2x bhalf8 each)
  const int brow = t >> 2;
  const int bk   = (t & 3) * 16;
  const short* BhR = Ath + (size_t)(n0 + brow) * P;
  const short* BlR = Atl + (size_t)(n0 + brow) * P;

  const int l = t & 63, w = t >> 6;
  const int wr = (w & 1) * 16, wc = (w >> 1) * 32;
  const int fr = l & 15, ko8 = (l >> 4) * 8, rq = (l >> 4) * 4;

  f32x4 acc[2];
  acc[0] = (f32x4){0.f, 0.f, 0.f, 0.f};
  acc[1] = (f32x4){0.f, 0.f, 0.f, 0.f};

  bhalf8 pah, pal, pbh0, pbh1, pbl0, pbl1;
  pah  = *(const bhalf8*)(AhR + ak);
  pal  = *(const bhalf8*)(AlR + ak);
  pbh0 = *(const bhalf8*)(BhR + bk);
  pbh1 = *(const bhalf8*)(BhR + bk + 8);
  pbl0 = *(const bhalf8*)(BlR + bk);
  pbl1 = *(const bhalf8*)(BlR + bk + 8);

#define STAGE1(buf)                                   \
  do {                                                \
    *(bhalf8*)&As_h[buf][arow][ak]    = pah;          \
    *(bhalf8*)&As_l[buf][arow][ak]    = pal;          \
    *(bhalf8*)&Bs_h[buf][brow][bk]    = pbh0;         \
    *(bhalf8*)&Bs_h[buf][brow][bk+8]  = pbh1;         \
    *(bhalf8*)&Bs_l[buf][brow][bk]    = pbl0;         \
    *(bhalf8*)&Bs_l[buf][brow][bk+8]  = pbl1;         \
  } while (0)

  STAGE1(0);

  for (int ks = 0; ks < 16; ++ks) {
    const int b = ks & 1;
    if (ks < 15) {
      const int kn = (ks + 1) * 64;
      pah  = *(const bhalf8*)(AhR + kn + ak);
      pal  = *(const bhalf8*)(AlR + kn + ak);
      pbh0 = *(const bhalf8*)(BhR + kn + bk);
      pbh1 = *(const bhalf8*)(BhR + kn + bk + 8);
      pbl0 = *(const bhalf8*)(BlR + kn + bk);
      pbl1 = *(const bhalf8*)(BlR + kn + bk + 8);
    }
    __syncthreads();
#pragma unroll
    for (int ks2 = 0; ks2 < 2; ++ks2) {
      const int ko = ks2 * 32 + ko8;
      bhalf8 ahv = *(const bhalf8*)&As_h[b][wr + fr][ko];
      bhalf8 alv = *(const bhalf8*)&As_l[b][wr + fr][ko];
#pragma unroll
      for (int ni = 0; ni < 2; ++ni) {
        bhalf8 bhv = *(const bhalf8*)&Bs_h[b][wc + ni * 16 + fr][ko];
        bhalf8 blv = *(const bhalf8*)&Bs_l[b][wc + ni * 16 + fr][ko];
        acc[ni] = __builtin_amdgcn_mfma_f32_16x16x32_bf16(ahv, bhv, acc[ni], 0, 0, 0);
        acc[ni] = __builtin_amdgcn_mfma_f32_16x16x32_bf16(ahv, blv, acc[ni], 0, 0, 0);
        acc[ni] = __builtin_amdgcn_mfma_f32_16x16x32_bf16(alv, bhv, acc[ni], 0, 0, 0);
      }
    }
    if (ks < 15) STAGE1((ks + 1) & 1);
  }
#undef STAGE1

#pragma unroll
  for (int ni = 0; ni < 2; ++ni) {
    const int col = n0 + wc + ni * 16 + fr;
#pragma unroll
    for (int r = 0; r < 4; ++r) {
      const int row = m0 + wr + rq + r;
      const float v = acc[ni][r];
      const float c = fminf(fmaxf(v, 0.0f), 1.0f);
      const short h  = f2bf(v);
      const short lo = f2bf(v - bf2f(h));
      LHh[(size_t)row * D + col] = h;
      LHl[(size_t)row * D + col] = lo;
      if (row < N) {
        out[OFF_XHAT + (size_t)row * D + col] = v;
        out[OFF_XBOX + (size_t)row * D + col] = c;
        U[(size_t)row * D + col] = expf(-TAU * c);
      } else {
        const size_t ry = (size_t)(row - N);
        out[OFF_YHAT + ry * D + col] = v;
        out[OFF_YBOX + ry * D + col] = c;
      }
    }
  }
}

// ---------------------------------------------------------------------------
// smooth: Y_pred[n][j] = (1/tau) * log( sum_i rcp(U[n][i] + V[i][j]) )
// 32n x 32j tile, micro 2n x 2j; grid (64, 8), 256 threads.
// Epilogue writes bf16 hi/lo of Y_pred into LHS rows 4096+.
// ---------------------------------------------------------------------------
__global__ __launch_bounds__(256) void smooth_kernel(
    const float* __restrict__ U, const float* __restrict__ V,
    float* __restrict__ ypred, short* __restrict__ LHh,
    short* __restrict__ LHl) {
  __shared__ float us[256][34];
  const int t = threadIdx.x;
  const int n0 = blockIdx.x * 32, j0 = blockIdx.y * 32;

  {
    const int sr = t & 31;            // n within tile
    const int si = (t >> 5) * 32;     // i-chunk
    const float* up = U + (size_t)(n0 + sr) * D + si;
#pragma unroll
    for (int q = 0; q < 32; q += 4) {
      float4 x = *(const float4*)(up + q);
      us[si + q + 0][sr] = x.x;
      us[si + q + 1][sr] = x.y;
      us[si + q + 2][sr] = x.z;
      us[si + q + 3][sr] = x.w;
    }
  }
  __syncthreads();

  const int jg = (t & 15) * 2;
  const int nn = (t >> 4) * 2;
  const float* vp = V + j0 + jg;

  float acc00 = 0.f, acc01 = 0.f, acc10 = 0.f, acc11 = 0.f;
#pragma unroll 8
  for (int i = 0; i < D; ++i) {
    float2 u2 = *(const float2*)&us[i][nn];
    float2 v2 = *(const float2*)(vp + (size_t)i * D);
    acc00 += __builtin_amdgcn_rcpf(u2.x + v2.x);
    acc01 += __builtin_amdgcn_rcpf(u2.x + v2.y);
    acc10 += __builtin_amdgcn_rcpf(u2.y + v2.x);
    acc11 += __builtin_amdgcn_rcpf(u2.y + v2.y);
  }

  float a[2][2] = {{acc00, acc01}, {acc10, acc11}};
#pragma unroll
  for (int pI = 0; pI < 2; ++pI) {
    const int row = n0 + nn + pI;
    float2 o;
    o.x = (1.0f / TAU) * logf(a[pI][0]);
    o.y = (1.0f / TAU) * logf(a[pI][1]);
    *(float2*)(ypred + (size_t)row * D + j0 + jg) = o;
    short2 h2, l2;
    h2.x = f2bf(o.x); l2.x = f2bf(o.x - bf2f(h2.x));
    h2.y = f2bf(o.y); l2.y = f2bf(o.y - bf2f(h2.y));
    const size_t lrow = (size_t)(2 * N + row) * D + j0 + jg;
    *(short2*)(LHh + lrow) = h2;
    *(short2*)(LHl + lrow) = l2;
  }
}

// ---------------------------------------------------------------------------
// GEMM2 (MFMA): C[6144][1024] = [X_hat;Y_hat;Y_pred] @ B, 3-term split.
// BM=128 BN=64 BK=32, 512 thr = 8 waves (4x2), wave tile 32x32 (2x2 frags):
// 12 MFMA per 8 LDS reads. dbuf, K=256 -> 8 steps. 60KB LDS -> 2 blocks/CU.
// grid 768 flat (48 m x 16 n), XCD-swizzled.
// ---------------------------------------------------------------------------
__global__ __launch_bounds__(512) void gemm2_mfma(
    const short* __restrict__ LHh, const short* __restrict__ LHl,
    const short* __restrict__ Bth, const short* __restrict__ Btl,
    float* __restrict__ rec) {
  __shared__ __align__(16) short As_h[2][128][40];
  __shared__ __align__(16) short As_l[2][128][40];
  __shared__ __align__(16) short Bs_h[2][64][40];
  __shared__ __align__(16) short Bs_l[2][64][40];

  const int t  = threadIdx.x;
  const int wg = xcd_swz(blockIdx.x, 768);
  const int m0 = (wg >> 4) * 128, n0 = (wg & 15) * 64;

  // A staging: 128 rows x 32 k, 4 lanes/row (bhalf8)
  const int arow = t >> 2;
  const int ak   = (t & 3) * 8;
  const short* AhR = LHh + (size_t)(m0 + arow) * D;
  const short* AlR = LHl + (size_t)(m0 + arow) * D;
  // B staging: 64 rows x 32 k, 8 lanes/row (short4)
  const int brow = t >> 3;
  const int bk   = (t & 7) * 4;
  const short* BhR = Bth + (size_t)(n0 + brow) * D;
  const short* BlR = Btl + (size_t)(n0 + brow) * D;

  const int l = t & 63, w = t >> 6;
  const int wr = (w & 3) * 32, wc = (w >> 2) * 32;
  const int fr = l & 15, ko8 = (l >> 4) * 8, rq = (l >> 4) * 4;

  f32x4 acc[2][2];
#pragma unroll
  for (int i = 0; i < 2; ++i)
#pragma unroll
    for (int j = 0; j < 2; ++j) acc[i][j] = (f32x4){0.f, 0.f, 0.f, 0.f};

  bhalf8 pah, pal;
  short4 pbh, pbl;
  pah = *(const bhalf8*)(AhR + ak);
  pal = *(const bhalf8*)(AlR + ak);
  pbh = *(const short4*)(BhR + bk);
  pbl = *(const short4*)(BlR + bk);

#define STAGE2(buf)                            \
  do {                                         \
    *(bhalf8*)&As_h[buf][arow][ak] = pah;      \
    *(bhalf8*)&As_l[buf][arow][ak] = pal;      \
    *(short4*)&Bs_h[buf][brow][bk] = pbh;      \
    *(short4*)&Bs_l[buf][brow][bk] = pbl;      \
  } while (0)

  STAGE2(0);

  for (int ks = 0; ks < 8; ++ks) {
    const int b = ks & 1;
    if (ks < 7) {
      const int kn = (ks + 1) * 32;
      pah = *(const bhalf8*)(AhR + kn + ak);
      pal = *(const bhalf8*)(AlR + kn + ak);
      pbh = *(const short4*)(BhR + kn + bk);
      pbl = *(const short4*)(BlR + kn + bk);
    }
    __syncthreads();
    bhalf8 ahv[2], alv[2], bhv[2], blv[2];
#pragma unroll
    for (int mi = 0; mi < 2; ++mi) {
      ahv[mi] = *(const bhalf8*)&As_h[b][wr + mi * 16 + fr][ko8];
      alv[mi] = *(const bhalf8*)&As_l[b][wr + mi * 16 + fr][ko8];
      bhv[mi] = *(const bhalf8*)&Bs_h[b][wc + mi * 16 + fr][ko8];
      blv[mi] = *(const bhalf8*)&Bs_l[b][wc + mi * 16 + fr][ko8];
    }
#pragma unroll
    for (int mi = 0; mi < 2; ++mi)
#pragma unroll
      for (int ni = 0; ni < 2; ++ni) {
        acc[mi][ni] = __builtin_amdgcn_mfma_f32_16x16x32_bf16(ahv[mi], bhv[ni], acc[mi][ni], 0, 0, 0);
        acc[mi][ni] = __builtin_amdgcn_mfma_f32_16x16x32_bf16(ahv[mi], blv[ni], acc[mi][ni], 0, 0, 0);
        acc[mi][ni] = __builtin_amdgcn_mfma_f32_16x16x32_bf16(alv[mi], bhv[ni], acc[mi][ni], 0, 0, 0);
      }
    if (ks < 7) STAGE2((ks + 1) & 1);
  }
#undef STAGE2

#pragma unroll
  for (int mi = 0; mi < 2; ++mi)
#pragma unroll
    for (int ni = 0; ni < 2; ++ni) {
      const int col = n0 + wc + ni * 16 + fr;
#pragma unroll
      for (int r = 0; r < 4; ++r) {
        const int row = m0 + wr + mi * 16 + rq + r;
        rec[(size_t)row * P + col] = acc[mi][ni][r];
      }
    }
}

// ---------------------------------------------------------------------------
extern "C" void kernel_launch(void* const* d_in, const int* in_sizes, int n_in,
                              void* d_out, int out_size, void* d_ws,
                              size_t ws_size, hipStream_t stream) {
  const float* S    = (const float*)d_in[0];
  const float* T    = (const float*)d_in[1];
  const float* A    = (const float*)d_in[2];
  const float* rawM = (const float*)d_in[3];
  const float* B    = (const float*)d_in[4];
  float* out = (float*)d_out;
  char* ws = (char*)d_ws;

  short* Ath = (short*)(ws + WS_ATH);
  short* Atl = (short*)(ws + WS_ATL);
  short* Bth = (short*)(ws + WS_BTH);
  short* Btl = (short*)(ws + WS_BTL);
  float* V   = (float*)(ws + WS_V);
  float* U   = (float*)(ws + WS_U);
  short* LHh = (short*)(ws + WS_LHH);
  short* LHl = (short*)(ws + WS_LHL);
  short* STh = (short*)(ws + WS_STH);
  short* STl = (short*)(ws + WS_STL);

  prep_all_kernel<<<1600, 256, 0, stream>>>(S, T, A, rawM, B, Ath, Atl, Bth,
                                            Btl, V, STh, STl);
  gemm1_mfma<<<512, 256, 0, stream>>>(STh, STl, Ath, Atl, out, U, LHh, LHl);
  smooth_kernel<<<dim3(64, 8), 256, 0, stream>>>(U, V, out + OFF_YPRED, LHh,
                                                 LHl);
  gemm2_mfma<<<768, 512, 0, stream>>>(LHh, LHl, Bth, Btl, out + OFF_SREC);
}